// Round 8
// baseline (212.073 us; speedup 1.0000x reference)
//
#include <hip/hip_runtime.h>
#include <hip/hip_bf16.h>

#define NN   8192
#define DIN  512
#define DOUT 256

typedef __attribute__((ext_vector_type(8)))  short s16x8;   // 8 bf16 (A/B frag)
typedef __attribute__((ext_vector_type(16))) float f32x16;  // 32x32 C/D frag

static __device__ __forceinline__ unsigned short f2bf(float f) {
    union { float f; unsigned u; } v; v.f = f;
    unsigned r = v.u + 0x7fffu + ((v.u >> 16) & 1u);   // RNE
    return (unsigned short)(r >> 16);
}

// ---------------- Kernel 1: Wh = feat@W (fp32 regs) -> WhT bf16, src/dst fused -------
__global__ __launch_bounds__(256) void k_wh2(const float* __restrict__ feat,
                                             const float* __restrict__ W,
                                             const float* __restrict__ a,
                                             unsigned short* __restrict__ WhT,
                                             float* __restrict__ src,
                                             float* __restrict__ dst) {
    __shared__ float lf[16 * DIN];                 // 32 KB
    __shared__ float red[2][4][16];
    const int tid = threadIdx.x;
    const int i0  = blockIdx.x * 16;
    const int w   = tid >> 6, lane = tid & 63;

    const float4* fsrc = (const float4*)(feat + (size_t)i0 * DIN);
    float4* fdst = (float4*)lf;
    #pragma unroll
    for (int q = 0; q < 8; ++q) fdst[tid + q * 256] = fsrc[tid + q * 256];
    __syncthreads();

    const int c = tid;
    float outs[16];
    #pragma unroll
    for (int r = 0; r < 16; ++r) outs[r] = 0.f;

    for (int k = 0; k < DIN; k += 4) {
        float w0 = W[(k + 0) * DOUT + c];
        float w1 = W[(k + 1) * DOUT + c];
        float w2 = W[(k + 2) * DOUT + c];
        float w3 = W[(k + 3) * DOUT + c];
        #pragma unroll
        for (int r = 0; r < 16; ++r) {
            float4 f = *(const float4*)&lf[r * DIN + k];   // broadcast read
            outs[r] = fmaf(f.x, w0, fmaf(f.y, w1, fmaf(f.z, w2, fmaf(f.w, w3, outs[r]))));
        }
    }

    unsigned short tb[16];
    #pragma unroll
    for (int r = 0; r < 16; ++r) tb[r] = f2bf(outs[r]);
    uint4* wt = (uint4*)(WhT + (size_t)c * NN + i0);
    wt[0] = *(uint4*)&tb[0];
    wt[1] = *(uint4*)&tb[8];

    // fused src/dst = Wh @ a halves (fp32, exact Wh from registers)
    const float as_ = a[c], ad_ = a[DOUT + c];
    #pragma unroll
    for (int r = 0; r < 16; ++r) {
        float s = outs[r] * as_;
        float d = outs[r] * ad_;
        #pragma unroll
        for (int off = 32; off; off >>= 1) {
            s += __shfl_xor(s, off);
            d += __shfl_xor(d, off);
        }
        if (lane == 0) { red[0][w][r] = s; red[1][w][r] = d; }
    }
    __syncthreads();
    if (tid < 16)
        src[i0 + tid] = red[0][0][tid] + red[0][1][tid] + red[0][2][tid] + red[0][3][tid];
    else if (tid < 32) {
        int r = tid - 16;
        dst[i0 + r] = red[1][0][r] + red[1][1][r] + red[1][2][r] + red[1][3][r];
    }
}

// ---------------- Kernel 1b: adj -> bitmask, LINEAR layout ---------------------------
// bits byte b of row = cols [b*8, b*8+8); bit jj = (adj[row][b*8+jj] > 0).
// Thread covers 128 contiguous bytes of adj (8 int4) -> one coalesced u32 store.
__global__ __launch_bounds__(256) void k_mask(const int* __restrict__ adj,
                                              unsigned char* __restrict__ bits) {
    const int row = blockIdx.x;
    const int tid = threadIdx.x;
    const int* base = adj + (size_t)row * NN + tid * 32;
    unsigned int u = 0;
    #pragma unroll
    for (int j = 0; j < 8; ++j) {
        int4 v = *(const int4*)(base + j * 4);
        unsigned int b = (v.x > 0 ? 1u : 0u) | (v.y > 0 ? 2u : 0u) |
                         (v.z > 0 ? 4u : 0u) | (v.w > 0 ? 8u : 0u);
        u |= b << (j * 4);
    }
    *(unsigned int*)(bits + (size_t)row * 1024 + tid * 4) = u;
}

// ---------------- Kernel 2: masked-exp GEMM, B-in-registers, P-only LDS --------------
// grid = 128 rt x 4 ks = 512 blocks (2/CU, VGPR-capped). block = 512 thr = 8 waves.
// BM=64 rows x 256 cols; wave = 64 rows x 32 cols (2 mt x 4 ksub, 32x32x16 MFMA).
// B-frag loaded straight from L2-resident WhT into VGPRs (no LDS slab, no gload_lds,
// no manual waitcnt). LDS = P dbuf 16 KB only. One __syncthreads per step (P handoff);
// its drain covers only L1-hit loads. P(t+1) build sits between B(t) issue and MFMA(t)
// to hide the ~300cy L2 latency.

#define STEP6(T, CUR)                                                                    \
{                                                                                        \
    /* issue B(T) frags (global, L2-hot): col = c0w+l31, k = T*64 + ks4*16 + lhi*8 */    \
    s16x8 bfr_[4];                                                                       \
    _Pragma("unroll")                                                                    \
    for (int ks4 = 0; ks4 < 4; ++ks4)                                                    \
        bfr_[ks4] = *(const s16x8*)(WhTb + (T) * 64 + ks4 * 16);                         \
    /* build P(T+1) -> Pl[CUR^1] (covers B latency) */                                   \
    if ((T) < 31) {                                                                      \
        const unsigned int m8_ = browp[((T) + 1) * 8];                                   \
        float4 d0_ = *(const float4*)(dstp + ((T) + 1) * 64);                            \
        float4 d1_ = *(const float4*)(dstp + ((T) + 1) * 64 + 4);                        \
        const float dd_[8] = {d0_.x, d0_.y, d0_.z, d0_.w, d1_.x, d1_.y, d1_.z, d1_.w};   \
        s16x8 pw_;                                                                       \
        _Pragma("unroll")                                                                \
        for (int jj = 0; jj < 8; ++jj) {                                                 \
            float x_ = si + dd_[jj];                                                     \
            x_ = fmaxf(x_, 0.2f * x_);                  /* leaky_relu 0.2 */             \
            float p_ = (m8_ >> jj) & 1u ? __expf(x_) : 0.f;  /* bounded: no max-sub */   \
            den += p_;                                                                   \
            pw_[jj] = (short)f2bf(p_);                                                   \
        }                                                                                \
        *(s16x8*)(Pl[(CUR) ^ 1] + pbyte) = pw_;                                          \
    }                                                                                    \
    /* MFMA(T): A from Pl[CUR] (built last step), B from regs */                         \
    _Pragma("unroll")                                                                    \
    for (int ks4 = 0; ks4 < 4; ++ks4) {                                                  \
        const int kbyte_ = ks4 * 32 + lhi * 16;                                          \
        _Pragma("unroll")                                                                \
        for (int mt = 0; mt < 2; ++mt) {                                                 \
            const int row_ = mt * 32 + l31;                                              \
            s16x8 afv_ = *(const s16x8*)(Pl[CUR] + row_ * 128 +                          \
                                         (kbyte_ ^ ((row_ & 7) << 4)));                  \
            acc[mt] = __builtin_amdgcn_mfma_f32_32x32x16_bf16(afv_, bfr_[ks4], acc[mt], 0, 0, 0); \
        }                                                                                \
    }                                                                                    \
    __syncthreads();   /* P[CUR] consumed; P[CUR^1] visible for next step */             \
}

__global__ __launch_bounds__(512, 4) void k_attn6(const unsigned char* __restrict__ bits,
                                                  const unsigned short* __restrict__ WhT,
                                                  const float* __restrict__ src,
                                                  const float* __restrict__ dstg,
                                                  float* __restrict__ denp,
                                                  float* __restrict__ part) {
    __shared__ __attribute__((aligned(16))) char Pl[2][8192];   // P slab [64 r][64 k] swz

    const int tid  = threadIdx.x;
    const int lane = tid & 63;
    const int w    = tid >> 6;
    const int l31  = lane & 31, lhi = lane >> 5;
    const int c0w  = w * 32;

    const int rt  = blockIdx.x & 127;
    const int ks  = blockIdx.x >> 7;           // 0..3
    const int kb0 = ks * 2048;

    // per-lane B base: column c0w+l31, k-offset lhi*8 within the chunk
    const unsigned short* WhTb = WhT + (size_t)(c0w + l31) * NN + kb0 + lhi * 8;

    // builder role: row r, k-block kb (8 consecutive k per step)
    const int r  = tid >> 3, kb = tid & 7;
    const int gr = rt * 64 + r;
    const float si = src[gr];
    const unsigned char* browp = bits + (size_t)gr * 1024 + ks * 256 + kb;  // +t*8 per step
    const float* dstp = dstg + kb0 + kb * 8;
    const int pbyte = r * 128 + ((kb * 16) ^ ((r & 7) << 4));

    f32x16 acc[2];
    #pragma unroll
    for (int mt = 0; mt < 2; ++mt)
        #pragma unroll
        for (int e = 0; e < 16; ++e) acc[mt][e] = 0.f;
    float den = 0.f;

    // prologue: build P(0) -> Pl[0]
    {
        const unsigned int m8 = browp[0];
        float4 d0 = *(const float4*)(dstp);
        float4 d1 = *(const float4*)(dstp + 4);
        const float dd[8] = {d0.x, d0.y, d0.z, d0.w, d1.x, d1.y, d1.z, d1.w};
        s16x8 pw;
        #pragma unroll
        for (int jj = 0; jj < 8; ++jj) {
            float x = si + dd[jj];
            x = fmaxf(x, 0.2f * x);
            float p = (m8 >> jj) & 1u ? __expf(x) : 0.f;
            den += p;
            pw[jj] = (short)f2bf(p);
        }
        *(s16x8*)(Pl[0] + pbyte) = pw;
    }
    __syncthreads();

    for (int tt = 0; tt < 16; ++tt) {
        STEP6(2 * tt,     0);
        STEP6(2 * tt + 1, 1);
    }

    // denominator: reduce over the 8 kb lanes (lane bits 0..2)
    den += __shfl_xor(den, 1);
    den += __shfl_xor(den, 2);
    den += __shfl_xor(den, 4);
    if ((tid & 7) == 0) denp[(size_t)ks * NN + gr] = den;

    // epilogue: C/D layout (m74/m101): col = lane&31, row = (reg&3)+8*(reg>>2)+4*lhi
    float* pp = part + (size_t)ks * (NN * DOUT);
    #pragma unroll
    for (int mt = 0; mt < 2; ++mt) {
        #pragma unroll
        for (int e = 0; e < 16; ++e) {
            const int row = rt * 64 + mt * 32 + (e & 3) + 8 * (e >> 2) + 4 * lhi;
            pp[(size_t)row * DOUT + c0w + l31] = acc[mt][e];
        }
    }
}

// ---------------- Kernel 3: out = elu( (sum_ks num) / (sum_ks den) ) -----------------
__global__ __launch_bounds__(256) void k_finish2(const float* __restrict__ part,
                                                 const float* __restrict__ denp,
                                                 float* __restrict__ out) {
    const int idx = blockIdx.x * 256 + threadIdx.x;   // float4 units
    const int row = idx >> 6;                          // 64 float4 per row
    float den = denp[row] + denp[NN + row] + denp[2 * NN + row] + denp[3 * NN + row];
    float rv = den > 0.f ? 1.f / den : 0.f;
    const int st = NN * DOUT / 4;
    const float4* p = (const float4*)part;
    float4 va = p[idx], vb = p[idx + st], vc = p[idx + 2 * st], vd = p[idx + 3 * st];
    float4 s;
    s.x = (va.x + vb.x + vc.x + vd.x) * rv;
    s.y = (va.y + vb.y + vc.y + vd.y) * rv;
    s.z = (va.z + vb.z + vc.z + vd.z) * rv;
    s.w = (va.w + vb.w + vc.w + vd.w) * rv;
    s.x = s.x > 0.f ? s.x : expm1f(s.x);
    s.y = s.y > 0.f ? s.y : expm1f(s.y);
    s.z = s.z > 0.f ? s.z : expm1f(s.z);
    s.w = s.w > 0.f ? s.w : expm1f(s.w);
    ((float4*)out)[idx] = s;
}

extern "C" void kernel_launch(void* const* d_in, const int* in_sizes, int n_in,
                              void* d_out, int out_size, void* d_ws, size_t ws_size,
                              hipStream_t stream) {
    const float* feat = (const float*)d_in[0];
    const int*   adj  = (const int*)d_in[1];
    const float* W    = (const float*)d_in[2];
    const float* a    = (const float*)d_in[3];
    float* out = (float*)d_out;

    char* ws = (char*)d_ws;
    unsigned short* WhT  = (unsigned short*)ws;               // 4 MB
    float*          src  = (float*)(ws + 4194304);            // 32 KB
    float*          dst  = (float*)(ws + 4227072);            // 32 KB
    float*          denp = (float*)(ws + 4259840);            // 128 KB
    unsigned char*  bits = (unsigned char*)(ws + 4390912);    // 8 MB
    float*          part = (float*)(ws + 12779520);           // 32 MB (4 x 8 MB)

    k_mask   <<<8192, 256, 0, stream>>>(adj, bits);
    k_wh2    <<<512,  256, 0, stream>>>(feat, W, a, WhT, src, dst);
    k_attn6  <<<512,  512, 0, stream>>>(bits, WhT, src, dst, denp, part);
    k_finish2<<<2048, 256, 0, stream>>>(part, denp, out);
}

// Round 9
// 206.262 us; speedup vs baseline: 1.0282x; 1.0282x over previous
//
#include <hip/hip_runtime.h>
#include <hip/hip_bf16.h>

#define NN   8192
#define DIN  512
#define DOUT 256

typedef __attribute__((ext_vector_type(8)))  short s16x8;   // 8 bf16 (A/B frag)
typedef __attribute__((ext_vector_type(16))) float f32x16;  // 32x32 C/D frag

static __device__ __forceinline__ unsigned short f2bf(float f) {
    union { float f; unsigned u; } v; v.f = f;
    unsigned r = v.u + 0x7fffu + ((v.u >> 16) & 1u);   // RNE
    return (unsigned short)(r >> 16);
}

static __device__ __forceinline__ void gload_lds16(const void* g, void* l) {
    __builtin_amdgcn_global_load_lds(
        (const __attribute__((address_space(1))) unsigned int*)g,
        (__attribute__((address_space(3))) unsigned int*)l, 16, 0, 0);
}

// ---------------- Kernel 1: Wh = feat@W (fp32 regs) -> WhT bf16, src/dst fused -------
__global__ __launch_bounds__(256) void k_wh2(const float* __restrict__ feat,
                                             const float* __restrict__ W,
                                             const float* __restrict__ a,
                                             unsigned short* __restrict__ WhT,
                                             float* __restrict__ src,
                                             float* __restrict__ dst) {
    __shared__ float lf[16 * DIN];                 // 32 KB
    __shared__ float red[2][4][16];
    const int tid = threadIdx.x;
    const int i0  = blockIdx.x * 16;
    const int w   = tid >> 6, lane = tid & 63;

    const float4* fsrc = (const float4*)(feat + (size_t)i0 * DIN);
    float4* fdst = (float4*)lf;
    #pragma unroll
    for (int q = 0; q < 8; ++q) fdst[tid + q * 256] = fsrc[tid + q * 256];
    __syncthreads();

    const int c = tid;
    float outs[16];
    #pragma unroll
    for (int r = 0; r < 16; ++r) outs[r] = 0.f;

    for (int k = 0; k < DIN; k += 4) {
        float w0 = W[(k + 0) * DOUT + c];
        float w1 = W[(k + 1) * DOUT + c];
        float w2 = W[(k + 2) * DOUT + c];
        float w3 = W[(k + 3) * DOUT + c];
        #pragma unroll
        for (int r = 0; r < 16; ++r) {
            float4 f = *(const float4*)&lf[r * DIN + k];   // broadcast read
            outs[r] = fmaf(f.x, w0, fmaf(f.y, w1, fmaf(f.z, w2, fmaf(f.w, w3, outs[r]))));
        }
    }

    unsigned short tb[16];
    #pragma unroll
    for (int r = 0; r < 16; ++r) tb[r] = f2bf(outs[r]);
    uint4* wt = (uint4*)(WhT + (size_t)c * NN + i0);
    wt[0] = *(uint4*)&tb[0];
    wt[1] = *(uint4*)&tb[8];

    // fused src/dst = Wh @ a halves (fp32, exact Wh from registers)
    const float as_ = a[c], ad_ = a[DOUT + c];
    #pragma unroll
    for (int r = 0; r < 16; ++r) {
        float s = outs[r] * as_;
        float d = outs[r] * ad_;
        #pragma unroll
        for (int off = 32; off; off >>= 1) {
            s += __shfl_xor(s, off);
            d += __shfl_xor(d, off);
        }
        if (lane == 0) { red[0][w][r] = s; red[1][w][r] = d; }
    }
    __syncthreads();
    if (tid < 16)
        src[i0 + tid] = red[0][0][tid] + red[0][1][tid] + red[0][2][tid] + red[0][3][tid];
    else if (tid < 32) {
        int r = tid - 16;
        dst[i0 + r] = red[1][0][r] + red[1][1][r] + red[1][2][r] + red[1][3][r];
    }
}

// ---------------- Kernel 1b: adj -> bitmask, LINEAR layout ---------------------------
__global__ __launch_bounds__(256) void k_mask(const int* __restrict__ adj,
                                              unsigned char* __restrict__ bits) {
    const int row = blockIdx.x;
    const int tid = threadIdx.x;
    const int* base = adj + (size_t)row * NN + tid * 32;
    unsigned int u = 0;
    #pragma unroll
    for (int j = 0; j < 8; ++j) {
        int4 v = *(const int4*)(base + j * 4);
        unsigned int b = (v.x > 0 ? 1u : 0u) | (v.y > 0 ? 2u : 0u) |
                         (v.z > 0 ? 4u : 0u) | (v.w > 0 ? 8u : 0u);
        u |= b << (j * 4);
    }
    *(unsigned int*)(bits + (size_t)row * 1024 + tid * 4) = u;
}

// ---------------- Kernel 2: masked-exp GEMM, XCD-pinned, 4 blocks/CU -----------------
// grid = 1024: xcd = bid&7 -> ks = xcd>>1 (k-split 4), cs = xcd&1 (col half),
// rt = bid>>3 (128 row tiles). Per-XCD working set: WhT slab 512 KB + bits 2 MB +
// dst 8 KB < 4 MB L2 -> all loop loads are XCD-local L2 hits.
// block = 256 thr = 4 waves; tile 64 rows x 128 cols; wave = 64r x 32c
// (2 m-tiles x 4 ksub, 32x32x16 MFMA). LDS 40 KB -> 4 blocks/CU.
// Bs dbuf, Pl single: 2 barriers/step (lgkm-only mid, vmcnt(0) end).
__global__ __launch_bounds__(256, 4) void k_attn8(const unsigned char* __restrict__ bits,
                                                  const unsigned short* __restrict__ WhT,
                                                  const float* __restrict__ src,
                                                  const float* __restrict__ dstg,
                                                  float* __restrict__ denp,
                                                  float* __restrict__ part) {
    __shared__ __attribute__((aligned(16))) char Bs[2][16384];  // [128 col][64 k] swz, dbuf
    __shared__ __attribute__((aligned(16))) char Pl[8192];      // [64 row][64 k] swz

    const int tid  = threadIdx.x;
    const int lane = tid & 63;
    const int w    = tid >> 6;
    const int l31  = lane & 31, lhi = lane >> 5;
    const int c0w  = w * 32;                       // wave's local col base (0..96)

    const int bid  = blockIdx.x;
    const int xcd  = bid & 7;
    const int ks   = xcd >> 1;                     // 0..3
    const int cs   = xcd & 1;                      // 0..1
    const int rt   = bid >> 3;                     // 0..127
    const int kb0  = ks * 2048;
    const int cbase = cs * 128;

    // builder role: row r (0..63), k-quarter kb (0..3) -> 16 k per step
    const int r  = tid >> 2, kb = tid & 3;
    const int gr = rt * 64 + r;
    const float si = src[gr];
    const unsigned char* browp = bits + (size_t)gr * 1024 + ks * 256 + kb * 2;  // +t*8
    const float* dstp = dstg + kb0 + kb * 16;                                    // +t*64
    const int pb0 = r * 128 + (((kb * 32)      ) ^ ((r & 7) << 4));
    const int pb1 = r * 128 + (((kb * 32) + 16 ) ^ ((r & 7) << 4));

    // B staging maps: 1024 16B-chunks, 4 per thread (pre-swizzled global source)
    const char* gsrcB[4];
    #pragma unroll
    for (int q = 0; q < 4; ++q) {
        int chunk = q * 256 + tid;
        int col   = chunk >> 3;
        int kbB   = ((chunk & 7) * 16) ^ ((col & 7) << 4);
        gsrcB[q]  = (const char*)WhT + ((size_t)(cbase + col) * NN + kb0) * 2 + kbB;
    }

    f32x16 acc[2];
    #pragma unroll
    for (int mt = 0; mt < 2; ++mt)
        #pragma unroll
        for (int e = 0; e < 16; ++e) acc[mt][e] = 0.f;
    float den = 0.f;

    // prologue: stage B(0) -> Bs[0]; build P(0) -> Pl
    #pragma unroll
    for (int q = 0; q < 4; ++q)
        gload_lds16(gsrcB[q], Bs[0] + (q * 256 + tid) * 16);
    {
        const unsigned int m16 = *(const unsigned short*)(browp);
        float4 pd[4];
        #pragma unroll
        for (int h = 0; h < 4; ++h) pd[h] = ((const float4*)(dstp))[h];
        const float* pdf = (const float*)pd;
        s16x8 pw0, pw1;
        #pragma unroll
        for (int jj = 0; jj < 8; ++jj) {
            float x0 = si + pdf[jj];
            x0 = fmaxf(x0, 0.2f * x0);
            float p0 = (m16 >> jj) & 1u ? __expf(x0) : 0.f;
            float x1 = si + pdf[8 + jj];
            x1 = fmaxf(x1, 0.2f * x1);
            float p1 = (m16 >> (8 + jj)) & 1u ? __expf(x1) : 0.f;
            den += p0 + p1;
            pw0[jj] = (short)f2bf(p0);
            pw1[jj] = (short)f2bf(p1);
        }
        *(s16x8*)(Pl + pb0) = pw0;
        *(s16x8*)(Pl + pb1) = pw1;
    }
    asm volatile("s_waitcnt vmcnt(0) lgkmcnt(0)" ::: "memory");
    __builtin_amdgcn_s_barrier();

    for (int t = 0; t < 32; ++t) {
        const int cur = t & 1;
        // phase A: stage B(t+1) -> Bs[cur^1] (stays in flight past barrier 1)
        if (t < 31) {
            #pragma unroll
            for (int q = 0; q < 4; ++q)
                gload_lds16(gsrcB[q] + (size_t)(t + 1) * 128,
                            Bs[cur ^ 1] + (q * 256 + tid) * 16);
        }
        // prefetch P(t+1) inputs (L2/L1-hot)
        unsigned int m16 = 0;
        float4 pd[4];
        if (t < 31) {
            m16 = *(const unsigned short*)(browp + (t + 1) * 8);
            #pragma unroll
            for (int h = 0; h < 4; ++h) pd[h] = ((const float4*)(dstp + (t + 1) * 64))[h];
        }
        // MFMA(t): A from Pl, B from Bs[cur]
        __builtin_amdgcn_s_setprio(1);
        #pragma unroll
        for (int ks4 = 0; ks4 < 4; ++ks4) {
            const int kbyte = ks4 * 32 + lhi * 16;
            const int colL  = c0w + l31;
            s16x8 bfv = *(const s16x8*)(Bs[cur] + colL * 128 + (kbyte ^ ((colL & 7) << 4)));
            #pragma unroll
            for (int mt = 0; mt < 2; ++mt) {
                const int rowL = mt * 32 + l31;
                s16x8 afv = *(const s16x8*)(Pl + rowL * 128 + (kbyte ^ ((rowL & 7) << 4)));
                acc[mt] = __builtin_amdgcn_mfma_f32_32x32x16_bf16(afv, bfv, acc[mt], 0, 0, 0);
            }
        }
        __builtin_amdgcn_s_setprio(0);
        // barrier 1: everyone's Pl reads are in-register (lgkm drained by MFMA deps)
        __builtin_amdgcn_sched_barrier(0);
        __builtin_amdgcn_s_barrier();
        __builtin_amdgcn_sched_barrier(0);
        // phase B: build P(t+1) -> Pl
        if (t < 31) {
            const float* pdf = (const float*)pd;
            s16x8 pw0, pw1;
            #pragma unroll
            for (int jj = 0; jj < 8; ++jj) {
                float x0 = si + pdf[jj];
                x0 = fmaxf(x0, 0.2f * x0);                       // leaky_relu 0.2
                float p0 = (m16 >> jj) & 1u ? __expf(x0) : 0.f;  // bounded: no max-sub
                float x1 = si + pdf[8 + jj];
                x1 = fmaxf(x1, 0.2f * x1);
                float p1 = (m16 >> (8 + jj)) & 1u ? __expf(x1) : 0.f;
                den += p0 + p1;
                pw0[jj] = (short)f2bf(p0);
                pw1[jj] = (short)f2bf(p1);
            }
            *(s16x8*)(Pl + pb0) = pw0;
            *(s16x8*)(Pl + pb1) = pw1;
        }
        // barrier 2: B(t+1) landed, P(t+1) visible
        asm volatile("s_waitcnt vmcnt(0) lgkmcnt(0)" ::: "memory");
        __builtin_amdgcn_s_barrier();
    }

    // denominator: thread covered 16 k/step; rows split over kb = tid&3 (lane bits 0,1)
    den += __shfl_xor(den, 1);
    den += __shfl_xor(den, 2);
    if (cs == 0 && (tid & 3) == 0) denp[(size_t)ks * NN + gr] = den;

    // epilogue: C/D layout (m74/m101): col = lane&31, row = (reg&3)+8*(reg>>2)+4*lhi
    float* pp = part + (size_t)ks * (NN * DOUT);
    #pragma unroll
    for (int mt = 0; mt < 2; ++mt) {
        #pragma unroll
        for (int e = 0; e < 16; ++e) {
            const int row = rt * 64 + mt * 32 + (e & 3) + 8 * (e >> 2) + 4 * lhi;
            pp[(size_t)row * DOUT + cbase + c0w + l31] = acc[mt][e];
        }
    }
}

// ---------------- Kernel 3: out = elu( (sum_ks num) / (sum_ks den) ) -----------------
__global__ __launch_bounds__(256) void k_finish2(const float* __restrict__ part,
                                                 const float* __restrict__ denp,
                                                 float* __restrict__ out) {
    const int idx = blockIdx.x * 256 + threadIdx.x;   // float4 units
    const int row = idx >> 6;                          // 64 float4 per row
    float den = denp[row] + denp[NN + row] + denp[2 * NN + row] + denp[3 * NN + row];
    float rv = den > 0.f ? 1.f / den : 0.f;
    const int st = NN * DOUT / 4;
    const float4* p = (const float4*)part;
    float4 va = p[idx], vb = p[idx + st], vc = p[idx + 2 * st], vd = p[idx + 3 * st];
    float4 s;
    s.x = (va.x + vb.x + vc.x + vd.x) * rv;
    s.y = (va.y + vb.y + vc.y + vd.y) * rv;
    s.z = (va.z + vb.z + vc.z + vd.z) * rv;
    s.w = (va.w + vb.w + vc.w + vd.w) * rv;
    s.x = s.x > 0.f ? s.x : expm1f(s.x);
    s.y = s.y > 0.f ? s.y : expm1f(s.y);
    s.z = s.z > 0.f ? s.z : expm1f(s.z);
    s.w = s.w > 0.f ? s.w : expm1f(s.w);
    ((float4*)out)[idx] = s;
}

extern "C" void kernel_launch(void* const* d_in, const int* in_sizes, int n_in,
                              void* d_out, int out_size, void* d_ws, size_t ws_size,
                              hipStream_t stream) {
    const float* feat = (const float*)d_in[0];
    const int*   adj  = (const int*)d_in[1];
    const float* W    = (const float*)d_in[2];
    const float* a    = (const float*)d_in[3];
    float* out = (float*)d_out;

    char* ws = (char*)d_ws;
    unsigned short* WhT  = (unsigned short*)ws;               // 4 MB
    float*          src  = (float*)(ws + 4194304);            // 32 KB
    float*          dst  = (float*)(ws + 4227072);            // 32 KB
    float*          denp = (float*)(ws + 4259840);            // 128 KB
    unsigned char*  bits = (unsigned char*)(ws + 4390912);    // 8 MB
    float*          part = (float*)(ws + 12779520);           // 32 MB (4 x 8 MB)

    k_mask   <<<8192, 256, 0, stream>>>(adj, bits);
    k_wh2    <<<512,  256, 0, stream>>>(feat, W, a, WhT, src, dst);
    k_attn8  <<<1024, 256, 0, stream>>>(bits, WhT, src, dst, denp, part);
    k_finish2<<<2048, 256, 0, stream>>>(part, denp, out);
}